// Round 1
// baseline (243.217 us; speedup 1.0000x reference)
//
#include <hip/hip_runtime.h>
#include <stdint.h>

#define OBS_DIM 568   // 36 + 28*19

typedef __attribute__((ext_vector_type(8))) short bf16x8;
typedef __attribute__((ext_vector_type(4))) float f32x4;

static __device__ __forceinline__ unsigned bf16pack(float a, float b) {
  unsigned ua = __float_as_uint(a), ub = __float_as_uint(b);
  ua = (ua + 0x7FFFu + ((ua >> 16) & 1u)) >> 16;   // RNE to bf16
  ub = (ub + 0x7FFFu + ((ub >> 16) & 1u)) >> 16;
  return ua | (ub << 16);
}

// ---- P1: fold all weight matmuls into M (64x64 fp32) and bias c (64) ----
// M[0..35]  = We[:36]@Wo[:64] + (Ws[:36]+Ws[36:72])@Wo[64:]
// M[36..63] = We[36:]@Wo[:64]
// c = be@Wo[:64] + bs@Wo[64:] + bo
__global__ void prek1(const float* __restrict__ We, const float* __restrict__ be,
                      const float* __restrict__ Ws, const float* __restrict__ bs,
                      const float* __restrict__ Wo, const float* __restrict__ bo,
                      float* __restrict__ Mf, float* __restrict__ cvec) {
  const int i = blockIdx.x;   // 0..63 M row
  const int h = threadIdx.x;  // 0..63 M col
  float acc = 0.f;
  for (int k = 0; k < 64; ++k) acc += We[i * 64 + k] * Wo[k * 64 + h];
  if (i < 36) {
    for (int k = 0; k < 64; ++k)
      acc += (Ws[i * 64 + k] + Ws[(36 + i) * 64 + k]) * Wo[(64 + k) * 64 + h];
  }
  Mf[i * 64 + h] = acc;
  if (i == 0) {
    float cc = bo[h];
    for (int k = 0; k < 64; ++k)
      cc += be[k] * Wo[k * 64 + h] + bs[k] * Wo[(64 + k) * 64 + h];
    cvec[h] = cc;
  }
}

// ---- P2: pack M into bf16 B-fragment layout for mfma_f32_16x16x32_bf16 ----
// frag f = kh*4+nt; lane l holds B[k0+e][nt*16+(l&15)], k0 = kh*32+(l>>4)*8
__global__ void prek2(const float* __restrict__ Mf, uint4* __restrict__ Mp) {
  const int idx = blockIdx.x * 64 + threadIdx.x;  // 0..511
  const int f = idx >> 6, l = idx & 63;
  const int kh = f >> 2, nt = f & 3;
  const int n = nt * 16 + (l & 15);
  const int k0 = kh * 32 + ((l >> 4) << 3);
  uint4 w;
  w.x = bf16pack(Mf[(k0 + 0) * 64 + n], Mf[(k0 + 1) * 64 + n]);
  w.y = bf16pack(Mf[(k0 + 2) * 64 + n], Mf[(k0 + 3) * 64 + n]);
  w.z = bf16pack(Mf[(k0 + 4) * 64 + n], Mf[(k0 + 5) * 64 + n]);
  w.w = bf16pack(Mf[(k0 + 6) * 64 + n], Mf[(k0 + 7) * 64 + n]);
  Mp[idx] = w;
}

// stage one column-chunk (64 rows x up to 36 floats, stored [64][36]) via
// global_load_lds. LDS dest is linear (base + lane*16); per-lane global src
// maps dest slot (r,q) -> row r0+r, col cb + 4*min(q, maxq). Pad slots (q>6
// for 28-wide chunks) re-read the q=6 line (same cache line, no extra HBM).
static __device__ __forceinline__ void stage_chunk(const float* __restrict__ X,
                                                   int r0, int cb, int clampq,
                                                   float* ldsbase, int lane) {
#pragma unroll
  for (int i = 0; i < 9; ++i) {
    const int t = i * 64 + lane;
    const int r = (t * 7282) >> 16;  // t/9, exact for t < 32768
    int q = t - 9 * r;
    if (clampq && q > 6) q = 6;
    const float* src = X + (size_t)(r0 + r) * OBS_DIM + cb + q * 4;
    __builtin_amdgcn_global_load_lds(
        (const __attribute__((address_space(1))) float*)src,
        (__attribute__((address_space(3))) float*)(ldsbase + i * 256), 16, 0, 0);
  }
}

__global__ __launch_bounds__(64, 1) void gat_main(const float* __restrict__ X,
                                                  const float* __restrict__ Wa,
                                                  const uint4* __restrict__ Mp,
                                                  const float* __restrict__ cvec,
                                                  float* __restrict__ out) {
  // one wave per block; two private chunk buffers [64 rows][36 floats]
  __shared__ __align__(16) float buf[2][2304];
  const int lane = threadIdx.x;
  const int r0 = blockIdx.x * 64;

  float wa2[28];
#pragma unroll
  for (int m = 0; m < 28; ++m) wa2[m] = Wa[36 + m];  // uniform -> scalar loads

  float wavg[28];
#pragma unroll
  for (int m = 0; m < 28; ++m) wavg[m] = 0.f;
  float psum = 0.f;

  stage_chunk(X, r0, 36, 1, &buf[0][0], lane);  // chunk 0 (other j=0)

  for (int j = 0; j < 19; ++j) {
    if (j < 18)
      stage_chunk(X, r0, 36 + 28 * (j + 1), 1, &buf[(j + 1) & 1][0], lane);
    else
      stage_chunk(X, r0, 0, 0, &buf[1][0], lane);  // self chunk -> buf[1]
    // counted wait: the 9 newest (next chunk) may stay in flight
    asm volatile("s_waitcnt vmcnt(9)" ::: "memory");
    __builtin_amdgcn_sched_barrier(0);

    const float4* row = (const float4*)(&buf[j & 1][0] + lane * 36);
    float o[28];
#pragma unroll
    for (int q = 0; q < 7; ++q) {
      float4 v = row[q];
      o[4 * q + 0] = v.x; o[4 * q + 1] = v.y;
      o[4 * q + 2] = v.z; o[4 * q + 3] = v.w;
    }
    // logit = other_j . Wa2  (self/ba terms cancel in softmax)
    float da = 0.f, db = 0.f, dc = 0.f, dd = 0.f;
#pragma unroll
    for (int q = 0; q < 7; ++q) {
      da += o[4 * q + 0] * wa2[4 * q + 0];
      db += o[4 * q + 1] * wa2[4 * q + 1];
      dc += o[4 * q + 2] * wa2[4 * q + 2];
      dd += o[4 * q + 3] * wa2[4 * q + 3];
    }
    const float p = __expf((da + db) + (dc + dd));  // |logit| ~<4, no max needed
    psum += p;
#pragma unroll
    for (int m = 0; m < 28; ++m) wavg[m] += p * o[m];
  }

  asm volatile("s_waitcnt vmcnt(0)" ::: "memory");
  __builtin_amdgcn_sched_barrier(0);

  // self chunk from buf[1]
  const float4* srow = (const float4*)(&buf[1][0] + lane * 36);
  float s[36];
#pragma unroll
  for (int q = 0; q < 9; ++q) {
    float4 v = srow[q];
    s[4 * q + 0] = v.x; s[4 * q + 1] = v.y;
    s[4 * q + 2] = v.z; s[4 * q + 3] = v.w;
  }
  const float inv = 1.0f / psum;

  // z = [s(36), wavg*inv(28)] as bf16 into buf[0], row stride 36 floats
  unsigned pw[32];
#pragma unroll
  for (int t = 0; t < 18; ++t) pw[t] = bf16pack(s[2 * t], s[2 * t + 1]);
#pragma unroll
  for (int t = 0; t < 14; ++t)
    pw[18 + t] = bf16pack(wavg[2 * t] * inv, wavg[2 * t + 1] * inv);
  uint4* zw4 = (uint4*)(&buf[0][0] + lane * 36);
#pragma unroll
  for (int w = 0; w < 8; ++w) {
    uint4 v; v.x = pw[4 * w]; v.y = pw[4 * w + 1];
    v.z = pw[4 * w + 2]; v.w = pw[4 * w + 3];
    zw4[w] = v;
  }
  __syncthreads();  // single-wave block: cheap; orders z write -> A-frag read

  // out = z @ M + c via 16x16x32 bf16 MFMA (4 row-tiles x 4 col-tiles x 2 k)
  bf16x8 Bf[2][4];
#pragma unroll
  for (int kh = 0; kh < 2; ++kh)
#pragma unroll
    for (int nt = 0; nt < 4; ++nt) {
      uint4 v = Mp[(kh * 4 + nt) * 64 + lane];
      Bf[kh][nt] = __builtin_bit_cast(bf16x8, v);
    }
  float cb4[4];
#pragma unroll
  for (int nt = 0; nt < 4; ++nt) cb4[nt] = cvec[nt * 16 + (lane & 15)];

  const short* zbase = (const short*)&buf[0][0];
#pragma unroll
  for (int rt = 0; rt < 4; ++rt) {
    // A-frag: lane holds z[rt*16 + (lane&15)][(lane>>4)*8 + e], e=0..7
    const short* ap = zbase + (rt * 16 + (lane & 15)) * 72 + (lane >> 4) * 8;
    bf16x8 A0 = *(const bf16x8*)(ap);        // k = 0..31
    bf16x8 A1 = *(const bf16x8*)(ap + 32);   // k = 32..63
#pragma unroll
    for (int nt = 0; nt < 4; ++nt) {
      f32x4 acc = {cb4[nt], cb4[nt], cb4[nt], cb4[nt]};
      acc = __builtin_amdgcn_mfma_f32_16x16x32_bf16(A0, Bf[0][nt], acc, 0, 0, 0);
      acc = __builtin_amdgcn_mfma_f32_16x16x32_bf16(A1, Bf[1][nt], acc, 0, 0, 0);
      // C/D: col = lane&15, row = (lane>>4)*4 + e   [m89-verified]
      float* op = out + (size_t)(r0 + rt * 16 + (lane >> 4) * 4) * 64 +
                  nt * 16 + (lane & 15);
#pragma unroll
      for (int e = 0; e < 4; ++e) op[e * 64] = acc[e];
    }
  }
}

extern "C" void kernel_launch(void* const* d_in, const int* in_sizes, int n_in,
                              void* d_out, int out_size, void* d_ws, size_t ws_size,
                              hipStream_t stream) {
  const float* X  = (const float*)d_in[0];
  const float* Wa = (const float*)d_in[1];
  // d_in[2] = ba: cancels in softmax, unused
  const float* We = (const float*)d_in[3];
  const float* be = (const float*)d_in[4];
  const float* Ws = (const float*)d_in[5];
  const float* bs = (const float*)d_in[6];
  const float* Wo = (const float*)d_in[7];
  const float* bo = (const float*)d_in[8];
  float* out = (float*)d_out;

  char* ws = (char*)d_ws;
  uint4* Mp   = (uint4*)ws;                    // 8192 B packed bf16 B-frags
  float* Mf   = (float*)(ws + 8192);           // 16384 B fp32 M
  float* cvec = (float*)(ws + 8192 + 16384);   // 256 B bias

  const int nrows = in_sizes[0] / OBS_DIM;     // 65536

  prek1<<<64, 64, 0, stream>>>(We, be, Ws, bs, Wo, bo, Mf, cvec);
  prek2<<<8, 64, 0, stream>>>(Mf, Mp);
  gat_main<<<nrows / 64, 64, 0, stream>>>(X, Wa, Mp, cvec, out);
}